// Round 3
// baseline (283.459 us; speedup 1.0000x reference)
//
#include <hip/hip_runtime.h>

// Problem constants (from reference setup_inputs) — all tensors are float32.
#define B_DIM 2
#define C_DIM 64
#define N_DIM 1024
#define E_DIM 32
#define BE_DIM (B_DIM * E_DIM)   // 64
#define ITILE 16                 // rows of the N x N image per block

// 1/ln2 and 2/ln2 — fold sigmoid's exp into native exp2 (v_exp_f32).
#define RCP_LN2  1.4426950408889634f
#define TWO_RCP_LN2 2.8853900817779268f

// Native clang vector type: __builtin_nontemporal_store requires a vector of
// scalars, not HIP's float4 class type.
typedef float f32x4 __attribute__((ext_vector_type(4)));

// ---------------------------------------------------------------------------
// Kernel 1: t[b,e,n] = sum_c th12[e,c] * emb[b,c,n], for both parameter sets.
// UNCHANGED (control variable — known good, ~few µs).
// ---------------------------------------------------------------------------
__global__ __launch_bounds__(256) void compute_t_kernel(
    const float* __restrict__ emb,
    const float* __restrict__ th12_1,
    const float* __restrict__ th12_2,
    float* __restrict__ t1,
    float* __restrict__ t2)
{
    const int n  = blockIdx.x * 256 + threadIdx.x;
    const int be = blockIdx.y;
    const int b  = be >> 5;       // E=32
    const int e  = be & 31;

    const float* __restrict__ embp = emb + (size_t)b * C_DIM * N_DIM + n;
    const float* __restrict__ w1   = th12_1 + e * C_DIM;
    const float* __restrict__ w2   = th12_2 + e * C_DIM;

    float acc1 = 0.f, acc2 = 0.f;
#pragma unroll
    for (int c = 0; c < C_DIM; ++c) {
        const float x = embp[(size_t)c * N_DIM];
        acc1 = fmaf(w1[c], x, acc1);
        acc2 = fmaf(w2[c], x, acc2);
    }
    t1[be * N_DIM + n] = acc1;
    t2[be * N_DIM + n] = acc2;
}

// ---------------------------------------------------------------------------
// Kernel 2: out[b,e,i,j] = relu(2*max(t1i,t1j) + th5_1[e]*(i==j))
//                        * sigmoid(relu(2*max(t2i,t2j) + th5_2[e]*(i==j)))
//
// Round-2 changes (theory: streaming-write efficiency, not dispatch count):
//  - NONTEMPORAL f32x4 stores: out (268 MB) is write-once; nt stores avoid
//    L2/L3 write-allocate thrash (out ~= L3 capacity).
//  - Gate side pre-scaled by 2/ln2: sigmoid(relu(2m+th5)) ==
//    rcp(1 + exp2(-relu((2/ln2)m + th5/ln2))), since relu commutes with
//    positive scaling. v_exp_f32 IS exp2 -> saves a multiply/elem and any
//    division sequence (rcp via __builtin_amdgcn_rcpf, tol 0.125 is ample).
//  - Diagonal fix moved out of the hot loop: on the diagonal t[j]==t[i], so
//    the fixup needs no per-k selects; <=1 thread per row takes the branch
//    (execz-skipped elsewhere).
// ---------------------------------------------------------------------------
__global__ __launch_bounds__(256) void edge_kernel(
    const float* __restrict__ t1,
    const float* __restrict__ t2,
    const float* __restrict__ th5_1,
    const float* __restrict__ th5_2,
    float* __restrict__ out)
{
    const int be = blockIdx.y;
    const int e  = be & (E_DIM - 1);
    const int i0 = blockIdx.x * ITILE;
    const int jb = threadIdx.x * 4;

    const float* __restrict__ t1r = t1 + be * N_DIM;
    const float* __restrict__ t2r = t2 + be * N_DIM;

    const float th51  = th5_1[e];
    const float th52s = th5_2[e] * RCP_LN2;     // scaled diagonal term (gate)

    const f32x4 a = *reinterpret_cast<const f32x4*>(t1r + jb);
    const f32x4 g = *reinterpret_cast<const f32x4*>(t2r + jb);

    // adj side: 2*t1[j].  gate side: (2/ln2)*t2[j].
    const float a2[4] = {a.x + a.x, a.y + a.y, a.z + a.z, a.w + a.w};
    const float gs[4] = {g.x * TWO_RCP_LN2, g.y * TWO_RCP_LN2,
                         g.z * TWO_RCP_LN2, g.w * TWO_RCP_LN2};

    // Per-row uniform scalars (addresses are block-uniform + constant -> s_load).
    float t1i2[ITILE], t2is[ITILE];
#pragma unroll
    for (int r = 0; r < ITILE; ++r) {
        t1i2[r] = 2.f * t1r[i0 + r];
        t2is[r] = TWO_RCP_LN2 * t2r[i0 + r];
    }

    float* dst = out + ((size_t)be * N_DIM + i0) * N_DIM + jb;

#pragma unroll
    for (int r = 0; r < ITILE; ++r) {
        const int i = i0 + r;

        f32x4 o;
#pragma unroll
        for (int k = 0; k < 4; ++k) {
            const float adj = fmaxf(fmaxf(t1i2[r], a2[k]), 0.f);
            const float y   = fmaxf(fmaxf(t2is[r], gs[k]), 0.f);
            const float gate = __builtin_amdgcn_rcpf(1.f + exp2f(-y));
            o[k] = adj * gate;
        }

        // Diagonal: j == i lies in this thread's 4-wide range for <=1 thread
        // per row. There, max(t[i],t[j]) == t[i], so no array access needed.
        const int kd = i - jb;
        if ((unsigned)kd < 4u) {
            const float adjd = fmaxf(t1i2[r] + th51, 0.f);
            const float yd   = fmaxf(t2is[r] + th52s, 0.f);
            const float dv   = adjd * __builtin_amdgcn_rcpf(1.f + exp2f(-yd));
            o[kd] = dv;
        }

        __builtin_nontemporal_store(o,
            reinterpret_cast<f32x4*>(dst + (size_t)r * N_DIM));
    }
}

// ---------------------------------------------------------------------------
extern "C" void kernel_launch(void* const* d_in, const int* in_sizes, int n_in,
                              void* d_out, int out_size, void* d_ws, size_t ws_size,
                              hipStream_t stream) {
    const float* emb    = (const float*)d_in[0];
    const float* th12_1 = (const float*)d_in[1];
    // d_in[2] = th34_1 (unused by reference)
    const float* th5_1  = (const float*)d_in[3];
    const float* th12_2 = (const float*)d_in[4];
    // d_in[5] = th34_2 (unused by reference)
    const float* th5_2  = (const float*)d_in[6];
    float* out = (float*)d_out;

    float* t1 = (float*)d_ws;                       // BE*N floats = 256 KB
    float* t2 = t1 + (size_t)BE_DIM * N_DIM;        // another 256 KB

    dim3 g1(N_DIM / 256, BE_DIM);
    compute_t_kernel<<<g1, 256, 0, stream>>>(emb, th12_1, th12_2, t1, t2);

    dim3 g2(N_DIM / ITILE, BE_DIM);
    edge_kernel<<<g2, 256, 0, stream>>>(t1, t2, th5_1, th5_2, out);
}